// Round 4
// baseline (5314.488 us; speedup 1.0000x reference)
//
#include <hip/hip_runtime.h>

#define TT 2048
#define WD 768
#define HH 512
#define G4 2048      // 4*H
#define NC 5
#define SENT 0xFFFFFFFFu   // owned sentinel (-NaN); |h|<1 can never produce it.
                           // mailbox buffers memset to 0xFF at every launch.

typedef float f4 __attribute__((ext_vector_type(4)));
typedef unsigned int u4 __attribute__((ext_vector_type(4)));

// ---------------------------------------------------------------------------
// Kernel 1: zin[t][g] = emb[sent[t]] . Wih[g] + bih[g] + bhh[g]   (both dirs)
// ---------------------------------------------------------------------------
__global__ __launch_bounds__(256) void zin_gemm(
    const int* __restrict__ sent, const float* __restrict__ emb,
    const float* __restrict__ Wih_f, const float* __restrict__ bih_f, const float* __restrict__ bhh_f,
    const float* __restrict__ Wih_b, const float* __restrict__ bih_b, const float* __restrict__ bhh_b,
    float* __restrict__ zin_f, float* __restrict__ zin_b)
{
    const int dirn = blockIdx.z;
    const float* Wih = dirn ? Wih_b : Wih_f;
    const float* bih = dirn ? bih_b : bih_f;
    const float* bhh = dirn ? bhh_b : bhh_f;
    float* zin = dirn ? zin_b : zin_f;

    __shared__ float As[16][128];
    __shared__ float Bs[16][128];

    const int tid = threadIdx.x;
    const int t0 = blockIdx.y * 128;
    const int g0 = blockIdx.x * 128;
    const int tm = tid >> 4, tn = tid & 15;

    float acc[8][8];
#pragma unroll
    for (int a = 0; a < 8; a++)
#pragma unroll
        for (int b = 0; b < 8; b++) acc[a][b] = 0.f;

    for (int kt = 0; kt < 48; ++kt) {
        const int k0 = kt * 16;
#pragma unroll
        for (int u = 0; u < 2; ++u) {
            const int s = tid * 2 + u;
            const int m = s >> 2, kq = s & 3;
            const int rowA = sent[t0 + m];
            float4 av = *(const float4*)(emb + (size_t)rowA * WD + k0 + kq * 4);
            As[kq * 4 + 0][m] = av.x; As[kq * 4 + 1][m] = av.y;
            As[kq * 4 + 2][m] = av.z; As[kq * 4 + 3][m] = av.w;
            float4 bv = *(const float4*)(Wih + (size_t)(g0 + m) * WD + k0 + kq * 4);
            Bs[kq * 4 + 0][m] = bv.x; Bs[kq * 4 + 1][m] = bv.y;
            Bs[kq * 4 + 2][m] = bv.z; Bs[kq * 4 + 3][m] = bv.w;
        }
        __syncthreads();
#pragma unroll
        for (int kk = 0; kk < 16; ++kk) {
            float4 a0 = *(const float4*)&As[kk][tm * 8];
            float4 a1 = *(const float4*)&As[kk][tm * 8 + 4];
            float4 b0 = *(const float4*)&Bs[kk][tn * 8];
            float4 b1 = *(const float4*)&Bs[kk][tn * 8 + 4];
            float av8[8] = {a0.x, a0.y, a0.z, a0.w, a1.x, a1.y, a1.z, a1.w};
            float bv8[8] = {b0.x, b0.y, b0.z, b0.w, b1.x, b1.y, b1.z, b1.w};
#pragma unroll
            for (int a = 0; a < 8; a++)
#pragma unroll
                for (int b = 0; b < 8; b++) acc[a][b] += av8[a] * bv8[b];
        }
        __syncthreads();
    }
    float bias[8];
#pragma unroll
    for (int b = 0; b < 8; b++) { int g = g0 + tn * 8 + b; bias[b] = bih[g] + bhh[g]; }
#pragma unroll
    for (int a = 0; a < 8; a++) {
        const int t = t0 + tm * 8 + a;
        float* op = zin + (size_t)t * G4 + g0 + tn * 8;
        float4 o0 = {acc[a][0] + bias[0], acc[a][1] + bias[1], acc[a][2] + bias[2], acc[a][3] + bias[3]};
        float4 o1 = {acc[a][4] + bias[4], acc[a][5] + bias[5], acc[a][6] + bias[6], acc[a][7] + bias[7]};
        *(float4*)op = o0; *(float4*)(op + 4) = o1;
    }
}

// ---------------------------------------------------------------------------
// Kernel 2: LSTM recurrence — private-mailbox edition.
//
// R0-R3 evidence: the handoff is bottlenecked by POLL SELF-CONGESTION, not
// detection rate (R3: faster polling = slower) and not cache scope (R1/R2).
// sc0 sc1 bypass loads are serviced per-request at the fabric (FETCH_SIZE
// scales with request count), and with all 64 wgs hammering the SAME 16-32
// cache lines of the shared h row, requests serialize at the TCC/MALL ports.
//
// Fix: replicate. Each producer writes its 16 h values to 32 PER-CONSUMER
// mailbox replicas (all-distinct lines, spread across TCC channels); each
// consumer polls only its private 2 KB. No line is ever touched by two wgs'
// polls -> uncontended fabric RT instead of serialized hot-line RT.
//
//  * Mailbox ring: mb[dir][consumer j][slot t&63][512 units] f32 (4 MB/dir).
//    Producer k at step t: h unit k*16+u -> mb[d][j][t&63][k*16+u], all j.
//    (8 coalesced 64B stores per wave0, values fanned via __shfl.)
//  * Consumer j step t: waves each poll own 512B chunk (lanes r<32, dwordx4
//    per lane, per-lane spin), then RESET their bytes to the sentinel (sc1)
//    for slot reuse 64 steps later (63-step reuse distance; per-step
//    vmcnt(0) drains guarantee ordering; sc1 everywhere -> no dirty-L2
//    writeback hazard).
//  * All protocol instructions are the R0-proven ones: sc1 stores,
//    sc0 sc1 poll loads, write-once sentinel values.
//  * hw[t][512] (packed) is still written (plain agent store) for the feats
//    kernel only — nobody polls it.
//  * R3's validated structure kept: no B1 (wave-private LDS chunks),
//    zb ping-pong, ONE barrier per step. Numerics bit-identical to R0.
// ---------------------------------------------------------------------------
__global__ __launch_bounds__(256, 1) void lstm_rec(
    const float* __restrict__ zin_f, const float* __restrict__ zin_b,
    const float* __restrict__ Whh_f, const float* __restrict__ Whh_b,
    unsigned int* __restrict__ hw_f, unsigned int* __restrict__ hw_b,
    unsigned int* __restrict__ mb_f, unsigned int* __restrict__ mb_b)
{
    const int bid = blockIdx.x;
    const int d = bid >> 5;          // 0 fwd, 1 bwd
    const int k = bid & 31;
    const float* zin = d ? zin_b : zin_f;
    const float* Whh = d ? Whh_b : Whh_f;
    unsigned int* hw = d ? hw_b : hw_f;
    unsigned int* mb = d ? mb_b : mb_f;

    const int tid = threadIdx.x;
    const int q = tid >> 6;          // wave = column segment (128 cols)
    const int r = tid & 63;          // lane within wave
    const int gate = r >> 4, jj = r & 15;
    const int grow = gate * HH + k * 16 + jj;      // global gate row [0,2048)

    const f4* wp = (const f4*)(Whh + (size_t)grow * HH + q * 128);
    f4 w[32];
#pragma unroll
    for (int i = 0; i < 32; ++i) w[i] = wp[i];     // plain loads: correct waitcnt
#pragma unroll
    for (int i = 0; i < 32; ++i)
        asm volatile("" : "+a"(w[i]));             // home the values in AGPRs

    __shared__ __align__(16) float hs[HH];
    __shared__ float zb[2][256];

    float c = 0.f;
    const int l = tid;               // wave0 lane id (used when tid<64)
    const int g = l >> 4, j = l & 15;     // gate / unit for gate phase
    const int n16 = k * 16 + j;           // hidden index for gate phase

    // poll geometry: lanes r<32 of wave q own units q*128 + r*4 .. +3
    // of THIS wg's private mailbox (consumer index k).
    unsigned int* const mbc = mb + (size_t)k * 64 * 512 + q * 128 + r * 4;

    for (int it = 0; it < TT; ++it) {
        const int t = d ? (TT - 1 - it) : it;

        // wave0: zin value for (gate g, unit j) — plain load issued before
        // the poll so its HBM latency overlaps the spin.
        float z = 0.f;
        if (tid < 64) z = zin[(size_t)t * G4 + g * HH + n16];

        if (it > 0 && r < 32) {
            const int tp = d ? (t + 1) : (t - 1);
            const int sl = tp & 63;
            const unsigned int* pp = mbc + (size_t)sl * 512;
            u4 v;
            for (;;) {
                asm volatile("global_load_dwordx4 %0, %1, off sc0 sc1\n\t"
                             "s_waitcnt vmcnt(0)"
                             : "=v"(v) : "v"(pp) : "memory");
                if (v.x != SENT && v.y != SENT && v.z != SENT && v.w != SENT) break;
            }
            // reset own 16B for slot reuse 64 steps later (sc1: write-through,
            // never dirty in an L2 -> no writeback-clobber hazard)
            const u4 sv = {SENT, SENT, SENT, SENT};
            asm volatile("global_store_dwordx4 %0, %1, off sc1"
                         :: "v"(pp), "v"(sv) : "memory");
            ((u4*)hs)[q * 32 + r] = v;     // wave-private chunk, wave-synchronous
        }

        // keep weights homed in AGPRs across the loop (re-pin each iter)
#pragma unroll
        for (int i = 0; i < 32; ++i) asm volatile("" : "+a"(w[i]));

        float part = 0.f;
        if (it > 0) {
            const f4* hv = ((const f4*)hs) + (q << 5);     // own chunk only
#pragma unroll
            for (int i = 0; i < 32; ++i) {
                f4 h4 = hv[i];
                part += w[i].x * h4.x + w[i].y * h4.y + w[i].z * h4.z + w[i].w * h4.w;
            }
        }
        zb[it & 1][tid] = part;
        __syncthreads();                                   // B2: partials ready

        if (tid < 64) {
            // same summation order as R0 (bit-exact): qq = 0..3
            const float* zbc = zb[it & 1];
            float s = zbc[l] + zbc[64 + l] + zbc[128 + l] + zbc[192 + l];
            const float pre = z + s;
            float act;
            if (g == 2) act = tanhf(pre);                  // g gate
            else        act = 1.f / (1.f + expf(-pre));    // i, f, o gates
            const float gi = __shfl(act, j);
            const float gf = __shfl(act, j + 16);
            const float gg = __shfl(act, j + 32);
            const float go = __shfl(act, j + 48);
            float hval = 0.f;
            if (l < 16) {
                c = gf * c + gi * gg;
                hval = go * tanhf(c);
                // packed h for the feats kernel (not polled by anyone)
                __hip_atomic_store(&hw[(size_t)t * HH + k * 16 + l],
                                   __float_as_uint(hval),
                                   __ATOMIC_RELAXED, __HIP_MEMORY_SCOPE_AGENT);
            }
            // fan out to the 32 private mailboxes: lane l carries the value
            // of unit (l&15); consumer jdx = (l>>4) + 4*jj2 -> 8 coalesced
            // 64B line-writes per store instruction group.
            const float hb = __shfl(hval, l & 15);
            const unsigned int hbits = __float_as_uint(hb);
            const int s2 = t & 63;
            unsigned int* mp = mb + (size_t)((l >> 4) * 64 + s2) * 512
                                  + k * 16 + (l & 15);
#pragma unroll
            for (int jj2 = 0; jj2 < 8; ++jj2) {
                __hip_atomic_store(mp + (size_t)jj2 * 4 * 64 * 512, hbits,
                                   __ATOMIC_RELAXED, __HIP_MEMORY_SCOPE_AGENT);
            }
        }
        // Cross-iteration safety without B1:
        //  * hs chunk q: written and read only by wave q, in program order.
        //  * zb: it+1 writes go to zb[(it+1)&1] != zb[it&1] read by wave0.
        //  * mailbox slot reuse: 63-step distance, stores drained by each
        //    step's vmcnt(0) poll waits.
    }
}

// ---------------------------------------------------------------------------
// Kernel 3: feats[t] = [h_f[t] | h_b[t]] . fc_w[i] + fc_b[i].  One wave per t.
// ---------------------------------------------------------------------------
__global__ void feats_kernel(const float* __restrict__ h_f, const float* __restrict__ h_b,
                             const float* __restrict__ fc_w, const float* __restrict__ fc_b,
                             float* __restrict__ feats)
{
    const int t = blockIdx.x;
    const int l = threadIdx.x;
    float acc[NC] = {0.f, 0.f, 0.f, 0.f, 0.f};
    for (int m = 0; m < 16; ++m) {
        const int cg = l + m * 64;
        const float hv = (cg < HH) ? h_f[(size_t)t * HH + cg]
                                   : h_b[(size_t)t * HH + cg - HH];
#pragma unroll
        for (int i = 0; i < NC; i++) acc[i] += hv * fc_w[i * (2 * HH) + cg];
    }
#pragma unroll
    for (int i = 0; i < NC; i++) {
#pragma unroll
        for (int off = 32; off; off >>= 1) acc[i] += __shfl_xor(acc[i], off);
    }
    if (l == 0) {
#pragma unroll
        for (int i = 0; i < NC; i++) feats[(size_t)t * NC + i] = acc[i] + fc_b[i];
    }
}

// ---------------------------------------------------------------------------
// Kernel 4: Viterbi forward + backtrack. 1 block, 64 threads.
// ---------------------------------------------------------------------------
__global__ void viterbi_kernel(const float* __restrict__ feats,
                               const float* __restrict__ trans,
                               float* __restrict__ out)
{
    __shared__ float fs[TT * NC];
    __shared__ int par[TT];
    __shared__ float pathv[TT];
    const int tid = threadIdx.x;
    for (int i = tid; i < TT * NC; i += 64) fs[i] = feats[i];
    float tr[25];
#pragma unroll
    for (int i = 0; i < 25; i++) tr[i] = trans[i];
    __syncthreads();

    float layer[NC];
#pragma unroll
    for (int i = 0; i < NC; i++) layer[i] = fs[i] + tr[i * 5 + 3];

    for (int s = 0; s < TT - 1; ++s) {
        const float* ft = &fs[(s + 1) * NC];
        float nl[NC]; int pk = 0;
#pragma unroll
        for (int i = 0; i < NC; i++) {
            float best = tr[i * 5 + 0] + layer[0]; int bj = 0;
#pragma unroll
            for (int jj = 1; jj < NC; jj++) {
                const float v = tr[i * 5 + jj] + layer[jj];
                if (v > best) { best = v; bj = jj; }
            }
            nl[i] = ft[i] + best;
            pk |= bj << (3 * i);
        }
#pragma unroll
        for (int i = 0; i < NC; i++) layer[i] = nl[i];
        if (tid == 0) par[s] = pk;
    }
    float best = layer[0] + tr[20]; int idx0 = 0;
#pragma unroll
    for (int jj = 1; jj < NC; jj++) {
        const float v = layer[jj] + tr[20 + jj];
        if (v > best) { best = v; idx0 = jj; }
    }
    __syncthreads();
    if (tid == 0) {
        pathv[TT - 1] = (float)idx0;
        int idx = idx0;
        for (int s = TT - 2; s >= 0; --s) {
            idx = (par[s] >> (3 * idx)) & 7;
            pathv[s] = (float)idx;
        }
        out[TT] = best;
    }
    __syncthreads();
    for (int i = tid; i < TT; i += 64) out[i] = pathv[i];
}

// ---------------------------------------------------------------------------
extern "C" void kernel_launch(void* const* d_in, const int* in_sizes, int n_in,
                              void* d_out, int out_size, void* d_ws, size_t ws_size,
                              hipStream_t stream) {
    const int*   sent   = (const int*)d_in[0];
    const float* emb    = (const float*)d_in[1];
    const float* Wih_f  = (const float*)d_in[2];
    const float* Whh_f  = (const float*)d_in[3];
    const float* bih_f  = (const float*)d_in[4];
    const float* bhh_f  = (const float*)d_in[5];
    const float* Wih_b  = (const float*)d_in[6];
    const float* Whh_b  = (const float*)d_in[7];
    const float* bih_b  = (const float*)d_in[8];
    const float* bhh_b  = (const float*)d_in[9];
    const float* fc_w   = (const float*)d_in[10];
    const float* fc_b   = (const float*)d_in[11];
    const float* trans  = (const float*)d_in[12];
    float* out = (float*)d_out;

    char* ws = (char*)d_ws;
    float* zin_f = (float*)ws;                                    // 16 MB @ 0
    float* zin_b = (float*)(ws + (size_t)16777216);               // 16 MB @ 16M
    unsigned int* hw_f = (unsigned int*)(ws + (size_t)33554432);  //  4 MB @ 32M (packed [t][512], feats only)
    unsigned int* hw_b = (unsigned int*)(ws + (size_t)37748736);  //  4 MB @ 36M
    unsigned int* mb_f = (unsigned int*)(ws + (size_t)41943040);  //  4 MB @ 40M (mailboxes [32][64][512])
    unsigned int* mb_b = (unsigned int*)(ws + (size_t)46137344);  //  4 MB @ 44M
    float* feats = (float*)(ws + (size_t)50331648);               // 40 KB @ 48M

    // OWN the sentinel: mailboxes = 0xFFFFFFFF (contiguous 8 MB).
    // hw_* needs no init: every dword is written every run.
    hipMemsetAsync(mb_f, 0xFF, (size_t)8388608, stream);

    dim3 gg(G4 / 128, TT / 128, 2);
    zin_gemm<<<gg, 256, 0, stream>>>(sent, emb, Wih_f, bih_f, bhh_f,
                                     Wih_b, bih_b, bhh_b, zin_f, zin_b);

    lstm_rec<<<64, 256, 0, stream>>>(zin_f, zin_b, Whh_f, Whh_b,
                                     hw_f, hw_b, mb_f, mb_b);

    feats_kernel<<<TT, 64, 0, stream>>>((const float*)hw_f, (const float*)hw_b,
                                        fc_w, fc_b, feats);

    viterbi_kernel<<<1, 64, 0, stream>>>(feats, trans, out);
}

// Round 5
// 4782.225 us; speedup vs baseline: 1.1113x; 1.1113x over previous
//
#include <hip/hip_runtime.h>

#define TT 2048
#define WD 768
#define HH 512
#define G4 2048      // 4*H
#define NC 5
#define SENT 0xFFFFFFFFu   // owned sentinel (-NaN); |h|<1 can never produce it.
                           // h buffers memset to 0xFF at every launch.

typedef float f4 __attribute__((ext_vector_type(4)));
typedef unsigned int u4 __attribute__((ext_vector_type(4)));

// ---------------------------------------------------------------------------
// Kernel 0: x[t] = emb[sent[t]]  — densify the embedding gather ONCE.
// zin_gemm previously re-gathered the same random 3KB rows 16x (one per
// g-tile) from the 98MB table with scattered 16B accesses. One coalesced
// pass into a 6MB dense buffer makes the GEMM's A-tiles stream from L2.
// ---------------------------------------------------------------------------
__global__ __launch_bounds__(192) void gather_x(
    const int* __restrict__ sent, const float* __restrict__ emb,
    float* __restrict__ x)
{
    const int t = blockIdx.x;            // [0, TT)
    const int l = threadIdx.x;           // 192 threads * float4 = 768 floats
    const float4 v = *(const float4*)(emb + (size_t)sent[t] * WD + l * 4);
    *(float4*)(x + (size_t)t * WD + l * 4) = v;
}

// ---------------------------------------------------------------------------
// Kernel 1: zin[t][g] = x[t] . Wih[g] + bih[g] + bhh[g]   (both dirs)
// Identical tile structure to the proven R0 GEMM; A now reads dense x.
// ---------------------------------------------------------------------------
__global__ __launch_bounds__(256) void zin_gemm(
    const float* __restrict__ x,
    const float* __restrict__ Wih_f, const float* __restrict__ bih_f, const float* __restrict__ bhh_f,
    const float* __restrict__ Wih_b, const float* __restrict__ bih_b, const float* __restrict__ bhh_b,
    float* __restrict__ zin_f, float* __restrict__ zin_b)
{
    const int dirn = blockIdx.z;
    const float* Wih = dirn ? Wih_b : Wih_f;
    const float* bih = dirn ? bih_b : bih_f;
    const float* bhh = dirn ? bhh_b : bhh_f;
    float* zin = dirn ? zin_b : zin_f;

    __shared__ float As[16][128];
    __shared__ float Bs[16][128];

    const int tid = threadIdx.x;
    const int t0 = blockIdx.y * 128;
    const int g0 = blockIdx.x * 128;
    const int tm = tid >> 4, tn = tid & 15;

    float acc[8][8];
#pragma unroll
    for (int a = 0; a < 8; a++)
#pragma unroll
        for (int b = 0; b < 8; b++) acc[a][b] = 0.f;

    for (int kt = 0; kt < 48; ++kt) {
        const int k0 = kt * 16;
#pragma unroll
        for (int u = 0; u < 2; ++u) {
            const int s = tid * 2 + u;
            const int m = s >> 2, kq = s & 3;
            float4 av = *(const float4*)(x + (size_t)(t0 + m) * WD + k0 + kq * 4);
            As[kq * 4 + 0][m] = av.x; As[kq * 4 + 1][m] = av.y;
            As[kq * 4 + 2][m] = av.z; As[kq * 4 + 3][m] = av.w;
            float4 bv = *(const float4*)(Wih + (size_t)(g0 + m) * WD + k0 + kq * 4);
            Bs[kq * 4 + 0][m] = bv.x; Bs[kq * 4 + 1][m] = bv.y;
            Bs[kq * 4 + 2][m] = bv.z; Bs[kq * 4 + 3][m] = bv.w;
        }
        __syncthreads();
#pragma unroll
        for (int kk = 0; kk < 16; ++kk) {
            float4 a0 = *(const float4*)&As[kk][tm * 8];
            float4 a1 = *(const float4*)&As[kk][tm * 8 + 4];
            float4 b0 = *(const float4*)&Bs[kk][tn * 8];
            float4 b1 = *(const float4*)&Bs[kk][tn * 8 + 4];
            float av8[8] = {a0.x, a0.y, a0.z, a0.w, a1.x, a1.y, a1.z, a1.w};
            float bv8[8] = {b0.x, b0.y, b0.z, b0.w, b1.x, b1.y, b1.z, b1.w};
#pragma unroll
            for (int a = 0; a < 8; a++)
#pragma unroll
                for (int b = 0; b < 8; b++) acc[a][b] += av8[a] * bv8[b];
        }
        __syncthreads();
    }
    float bias[8];
#pragma unroll
    for (int b = 0; b < 8; b++) { int g = g0 + tn * 8 + b; bias[b] = bih[g] + bhh[g]; }
#pragma unroll
    for (int a = 0; a < 8; a++) {
        const int t = t0 + tm * 8 + a;
        float* op = zin + (size_t)t * G4 + g0 + tn * 8;
        float4 o0 = {acc[a][0] + bias[0], acc[a][1] + bias[1], acc[a][2] + bias[2], acc[a][3] + bias[3]};
        float4 o1 = {acc[a][4] + bias[4], acc[a][5] + bias[5], acc[a][6] + bias[6], acc[a][7] + bias[7]};
        *(float4*)op = o0; *(float4*)(op + 4) = o1;
    }
}

// ---------------------------------------------------------------------------
// Kernel 2: LSTM recurrence — R0 protocol, VERBATIM (3869 us proven).
//
// R0-R4 conclusion: the handoff cost is the intrinsic store->LLC->load round
// trip. Poll request pressure is the enemy: every variant that raised it
// (R2 atomics, R3 2-deep/4-poller, R4 replicated mailboxes) was slower.
// R0's shape — ONE poller per CU, minimal hot lines, period ~= RT, probe IS
// the data transfer — is the optimum of this protocol class. Do not touch.
// ---------------------------------------------------------------------------
__global__ __launch_bounds__(256, 1) void lstm_rec(
    const float* __restrict__ zin_f, const float* __restrict__ zin_b,
    const float* __restrict__ Whh_f, const float* __restrict__ Whh_b,
    unsigned int* __restrict__ hw_f, unsigned int* __restrict__ hw_b)
{
    const int bid = blockIdx.x;
    const int d = bid >> 5;          // 0 fwd, 1 bwd
    const int k = bid & 31;
    const float* zin = d ? zin_b : zin_f;
    const float* Whh = d ? Whh_b : Whh_f;
    unsigned int* hw = d ? hw_b : hw_f;

    const int tid = threadIdx.x;
    const int q = tid >> 6;          // wave = column segment (128 cols)
    const int r = tid & 63;          // gate row within wg
    const int gate = r >> 4, jj = r & 15;
    const int grow = gate * HH + k * 16 + jj;      // global gate row [0,2048)

    const f4* wp = (const f4*)(Whh + (size_t)grow * HH + q * 128);
    f4 w[32];
#pragma unroll
    for (int i = 0; i < 32; ++i) w[i] = wp[i];     // plain loads: correct waitcnt
#pragma unroll
    for (int i = 0; i < 32; ++i)
        asm volatile("" : "+a"(w[i]));             // home the values in AGPRs

    __shared__ float hs[HH];
    __shared__ float zb[256];

    float c = 0.f;
    const int l = tid;               // wave0 lane id (used when tid<64)
    const int g = l >> 4, j = l & 15;     // gate / unit for gate phase
    const int n16 = k * 16 + j;           // hidden index for gate phase

    for (int it = 0; it < TT; ++it) {
        const int t = d ? (TT - 1 - it) : it;

        // wave0: zin value for (gate g, unit j) — issued before the poll
        float z = 0.f;
        if (tid < 64) z = zin[(size_t)t * G4 + g * HH + n16];

        if (it > 0 && tid < 64) {
            const int tp = d ? (t + 1) : (t - 1);
            const unsigned int* pa = hw + (size_t)tp * HH + l * 8;
            u4 a0, a1;
            for (;;) {
                asm volatile(
                    "global_load_dwordx4 %0, %2, off sc0 sc1\n\t"
                    "global_load_dwordx4 %1, %2, off offset:16 sc0 sc1\n\t"
                    "s_waitcnt vmcnt(0)"
                    : "=v"(a0), "=v"(a1) : "v"(pa) : "memory");
                if (a0.x != SENT && a0.y != SENT && a0.z != SENT && a0.w != SENT &&
                    a1.x != SENT && a1.y != SENT && a1.z != SENT && a1.w != SENT) break;
            }
            u4* hd = (u4*)(hs + l * 8);
            hd[0] = a0; hd[1] = a1;
        }
        __syncthreads();                                   // B1: hs ready

        // keep weights homed in AGPRs across the loop (re-pin each iter)
#pragma unroll
        for (int i = 0; i < 32; ++i) asm volatile("" : "+a"(w[i]));

        float part = 0.f;
        if (it > 0) {
            const f4* hv = ((const f4*)hs) + (q << 5);     // wave-uniform broadcast
#pragma unroll
            for (int i = 0; i < 32; ++i) {
                f4 h4 = hv[i];
                part += w[i].x * h4.x + w[i].y * h4.y + w[i].z * h4.z + w[i].w * h4.w;
            }
        }
        zb[tid] = part;                                    // zb[q*64 + r]
        __syncthreads();                                   // B2: partials ready

        if (tid < 64) {
            // same summation order as R6 (bit-exact): qq = 0..3
            float s = zb[l] + zb[64 + l] + zb[128 + l] + zb[192 + l];
            const float pre = z + s;
            float act;
            if (g == 2) act = tanhf(pre);                  // g gate
            else        act = 1.f / (1.f + expf(-pre));    // i, f, o gates
            const float gi = __shfl(act, j);
            const float gf = __shfl(act, j + 16);
            const float gg = __shfl(act, j + 32);
            const float go = __shfl(act, j + 48);
            if (l < 16) {
                c = gf * c + gi * gg;
                const float hval = go * tanhf(c);
                __hip_atomic_store(&hw[(size_t)t * HH + k * 16 + l],
                                   __float_as_uint(hval),
                                   __ATOMIC_RELAXED, __HIP_MEMORY_SCOPE_AGENT);
            }
        }
        // 2 barriers suffice: hs(it+1) writes (wave0, after B2(it)) cannot
        // race dot reads of hs(it) (before B2(it)); zb(it+1) writes (after
        // B1(it+1)) cannot race gate-phase zb reads (wave0 reaches B1(it+1)
        // only after finishing them).
    }
}

// ---------------------------------------------------------------------------
// Kernel 3: feats[t] = [h_f[t] | h_b[t]] . fc_w[i] + fc_b[i].  One wave per t.
// ---------------------------------------------------------------------------
__global__ void feats_kernel(const float* __restrict__ h_f, const float* __restrict__ h_b,
                             const float* __restrict__ fc_w, const float* __restrict__ fc_b,
                             float* __restrict__ feats)
{
    const int t = blockIdx.x;
    const int l = threadIdx.x;
    float acc[NC] = {0.f, 0.f, 0.f, 0.f, 0.f};
    for (int m = 0; m < 16; ++m) {
        const int cg = l + m * 64;
        const float hv = (cg < HH) ? h_f[(size_t)t * HH + cg]
                                   : h_b[(size_t)t * HH + cg - HH];
#pragma unroll
        for (int i = 0; i < NC; i++) acc[i] += hv * fc_w[i * (2 * HH) + cg];
    }
#pragma unroll
    for (int i = 0; i < NC; i++) {
#pragma unroll
        for (int off = 32; off; off >>= 1) acc[i] += __shfl_xor(acc[i], off);
    }
    if (l == 0) {
#pragma unroll
        for (int i = 0; i < NC; i++) feats[(size_t)t * NC + i] = acc[i] + fc_b[i];
    }
}

// ---------------------------------------------------------------------------
// Kernel 4: Viterbi forward + backtrack. 1 block, 64 threads.
// ---------------------------------------------------------------------------
__global__ void viterbi_kernel(const float* __restrict__ feats,
                               const float* __restrict__ trans,
                               float* __restrict__ out)
{
    __shared__ float fs[TT * NC];
    __shared__ int par[TT];
    __shared__ float pathv[TT];
    const int tid = threadIdx.x;
    for (int i = tid; i < TT * NC; i += 64) fs[i] = feats[i];
    float tr[25];
#pragma unroll
    for (int i = 0; i < 25; i++) tr[i] = trans[i];
    __syncthreads();

    float layer[NC];
#pragma unroll
    for (int i = 0; i < NC; i++) layer[i] = fs[i] + tr[i * 5 + 3];

    for (int s = 0; s < TT - 1; ++s) {
        const float* ft = &fs[(s + 1) * NC];
        float nl[NC]; int pk = 0;
#pragma unroll
        for (int i = 0; i < NC; i++) {
            float best = tr[i * 5 + 0] + layer[0]; int bj = 0;
#pragma unroll
            for (int jj = 1; jj < NC; jj++) {
                const float v = tr[i * 5 + jj] + layer[jj];
                if (v > best) { best = v; bj = jj; }
            }
            nl[i] = ft[i] + best;
            pk |= bj << (3 * i);
        }
#pragma unroll
        for (int i = 0; i < NC; i++) layer[i] = nl[i];
        if (tid == 0) par[s] = pk;
    }
    float best = layer[0] + tr[20]; int idx0 = 0;
#pragma unroll
    for (int jj = 1; jj < NC; jj++) {
        const float v = layer[jj] + tr[20 + jj];
        if (v > best) { best = v; idx0 = jj; }
    }
    __syncthreads();
    if (tid == 0) {
        pathv[TT - 1] = (float)idx0;
        int idx = idx0;
        for (int s = TT - 2; s >= 0; --s) {
            idx = (par[s] >> (3 * idx)) & 7;
            pathv[s] = (float)idx;
        }
        out[TT] = best;
    }
    __syncthreads();
    for (int i = tid; i < TT; i += 64) out[i] = pathv[i];
}

// ---------------------------------------------------------------------------
extern "C" void kernel_launch(void* const* d_in, const int* in_sizes, int n_in,
                              void* d_out, int out_size, void* d_ws, size_t ws_size,
                              hipStream_t stream) {
    const int*   sent   = (const int*)d_in[0];
    const float* emb    = (const float*)d_in[1];
    const float* Wih_f  = (const float*)d_in[2];
    const float* Whh_f  = (const float*)d_in[3];
    const float* bih_f  = (const float*)d_in[4];
    const float* bhh_f  = (const float*)d_in[5];
    const float* Wih_b  = (const float*)d_in[6];
    const float* Whh_b  = (const float*)d_in[7];
    const float* bih_b  = (const float*)d_in[8];
    const float* bhh_b  = (const float*)d_in[9];
    const float* fc_w   = (const float*)d_in[10];
    const float* fc_b   = (const float*)d_in[11];
    const float* trans  = (const float*)d_in[12];
    float* out = (float*)d_out;

    char* ws = (char*)d_ws;
    float* zin_f = (float*)ws;                                   // 16 MB @ 0
    float* zin_b = (float*)(ws + (size_t)16777216);              // 16 MB @ 16M
    unsigned int* hw_f = (unsigned int*)(ws + (size_t)33554432); //  4 MB @ 32M
    unsigned int* hw_b = (unsigned int*)(ws + (size_t)37748736); //  4 MB @ 36M
    float* feats = (float*)(ws + (size_t)41943040);              // 40 KB @ 40M
    float* x     = (float*)(ws + (size_t)42008576);              //  6 MB @ 40M+64K (dense emb[sent])

    // OWN the sentinel: h buffers = 0xFFFFFFFF (-NaN, impossible h)
    hipMemsetAsync(hw_f, 0xFF, (size_t)8388608, stream);         // covers hw_f + hw_b

    gather_x<<<TT, 192, 0, stream>>>(sent, emb, x);

    dim3 gg(G4 / 128, TT / 128, 2);
    zin_gemm<<<gg, 256, 0, stream>>>(x, Wih_f, bih_f, bhh_f,
                                     Wih_b, bih_b, bhh_b, zin_f, zin_b);

    lstm_rec<<<64, 256, 0, stream>>>(zin_f, zin_b, Whh_f, Whh_b, hw_f, hw_b);

    feats_kernel<<<TT, 64, 0, stream>>>((const float*)hw_f, (const float*)hw_b,
                                        fc_w, fc_b, feats);

    viterbi_kernel<<<1, 64, 0, stream>>>(feats, trans, out);
}

// Round 6
// 4780.574 us; speedup vs baseline: 1.1117x; 1.0003x over previous
//
#include <hip/hip_runtime.h>

#define TT 2048
#define WD 768
#define HH 512
#define G4 2048      // 4*H
#define NC 5
#define SENT 0xFFFFFFFFu   // owned sentinel (-NaN); |h|<1 can never produce it.
                           // h buffers memset to 0xFF at every launch.

typedef float f4 __attribute__((ext_vector_type(4)));
typedef unsigned int u4 __attribute__((ext_vector_type(4)));

// ---------------------------------------------------------------------------
// FUSED kernel: 576 wgs.
//   wgs   0..63 : LSTM recurrence — R0 protocol VERBATIM (3869-3875 us proven
//                 across R0/R5; R1-R4 proved every protocol variant is worse).
//                 Adds ONE readiness check per 128 steps (zin tile flag).
//   wgs 64..575 : zin GEMM — R0 arithmetic VERBATIM (bit-identical FMA order),
//                 t-tiles ordered fwd-ascending / bwd-descending so each
//                 direction's next tile is produced long before consumption.
//
// Rationale: lstm_rec runs at 7.8% VALUBusy / 0.27% HBM for 3875 us while 192
// CUs host nothing. The GEMM (~500-700 us standalone) is consumed in t-order
// at 242 us per 128-t tile -> fully hideable under the recurrence.
//
// Within-kernel zin visibility (no kernel-boundary flush available):
//   producer: sc1 stores (the R0-proven h-store path, write-through to LLC)
//             -> __syncthreads (drains vmcnt per wave) -> ONE device-scope
//             atomicAdd on zcnt[dir][ty] per wg.
//   consumer: sc0 sc1 poll of zcnt until ==16 (bypass loads, LLC-fresh),
//             then PLAIN zin loads: first touch of those lines on this CU/XCD
//             happens after the flag (caches invalidated at dispatch; same
//             mechanism R0-R5's cross-kernel zin handoff relied on), and sc1
//             write-through never leaves stale data in a producer L2.
// Deadlock-free: gemm wgs depend on nothing (always drain -> all 64 lstm wgs
// become resident); lstm wgs wait only on flags gemm unconditionally writes.
// ---------------------------------------------------------------------------
__global__ __launch_bounds__(256, 1) void fused_main(
    const int* __restrict__ sent, const float* __restrict__ emb,
    const float* __restrict__ Wih_f, const float* __restrict__ bih_f, const float* __restrict__ bhh_f,
    const float* __restrict__ Wih_b, const float* __restrict__ bih_b, const float* __restrict__ bhh_b,
    const float* __restrict__ Whh_f, const float* __restrict__ Whh_b,
    float* __restrict__ zin_f, float* __restrict__ zin_b,
    unsigned int* __restrict__ hw_f, unsigned int* __restrict__ hw_b,
    unsigned int* __restrict__ zcnt)
{
    __shared__ float As[16][128];
    __shared__ float Bs[16][128];
    __shared__ float hs[HH];
    __shared__ float zb[256];

    const int tid = threadIdx.x;

    if (blockIdx.x >= 64) {
        // ================= GEMM role =================
        const int lin  = blockIdx.x - 64;      // [0,512)
        const int pair = lin >> 5;             // [0,16): production order
        const int sub  = lin & 31;
        const int dirn = sub & 1;
        const int gx   = sub >> 1;             // [0,16)
        const int ty   = dirn ? (15 - pair) : pair;   // bwd consumes high t first

        const float* Wih = dirn ? Wih_b : Wih_f;
        const float* bih = dirn ? bih_b : bih_f;
        const float* bhh = dirn ? bhh_b : bhh_f;
        float* zin = dirn ? zin_b : zin_f;

        const int t0 = ty * 128;
        const int g0 = gx * 128;
        const int tm = tid >> 4, tn = tid & 15;

        float acc[8][8];
#pragma unroll
        for (int a = 0; a < 8; a++)
#pragma unroll
            for (int b = 0; b < 8; b++) acc[a][b] = 0.f;

        for (int kt = 0; kt < 48; ++kt) {
            const int k0 = kt * 16;
#pragma unroll
            for (int u = 0; u < 2; ++u) {
                const int s = tid * 2 + u;
                const int m = s >> 2, kq = s & 3;
                const int rowA = sent[t0 + m];
                float4 av = *(const float4*)(emb + (size_t)rowA * WD + k0 + kq * 4);
                As[kq * 4 + 0][m] = av.x; As[kq * 4 + 1][m] = av.y;
                As[kq * 4 + 2][m] = av.z; As[kq * 4 + 3][m] = av.w;
                float4 bv = *(const float4*)(Wih + (size_t)(g0 + m) * WD + k0 + kq * 4);
                Bs[kq * 4 + 0][m] = bv.x; Bs[kq * 4 + 1][m] = bv.y;
                Bs[kq * 4 + 2][m] = bv.z; Bs[kq * 4 + 3][m] = bv.w;
            }
            __syncthreads();
#pragma unroll
            for (int kk = 0; kk < 16; ++kk) {
                float4 a0 = *(const float4*)&As[kk][tm * 8];
                float4 a1 = *(const float4*)&As[kk][tm * 8 + 4];
                float4 b0 = *(const float4*)&Bs[kk][tn * 8];
                float4 b1 = *(const float4*)&Bs[kk][tn * 8 + 4];
                float av8[8] = {a0.x, a0.y, a0.z, a0.w, a1.x, a1.y, a1.z, a1.w};
                float bv8[8] = {b0.x, b0.y, b0.z, b0.w, b1.x, b1.y, b1.z, b1.w};
#pragma unroll
                for (int a = 0; a < 8; a++)
#pragma unroll
                    for (int b = 0; b < 8; b++) acc[a][b] += av8[a] * bv8[b];
            }
            __syncthreads();
        }
        float bias[8];
#pragma unroll
        for (int b = 0; b < 8; b++) { int g = g0 + tn * 8 + b; bias[b] = bih[g] + bhh[g]; }
#pragma unroll
        for (int a = 0; a < 8; a++) {
            const int t = t0 + tm * 8 + a;
            float* op = zin + (size_t)t * G4 + g0 + tn * 8;
            f4 o0 = {acc[a][0] + bias[0], acc[a][1] + bias[1], acc[a][2] + bias[2], acc[a][3] + bias[3]};
            f4 o1 = {acc[a][4] + bias[4], acc[a][5] + bias[5], acc[a][6] + bias[6], acc[a][7] + bias[7]};
            // sc1: write-through to LLC (within-kernel cross-XCD visibility)
            asm volatile("global_store_dwordx4 %0, %1, off sc1" :: "v"(op), "v"(o0) : "memory");
            asm volatile("global_store_dwordx4 %0, %1, off sc1" :: "v"(op + 4), "v"(o1) : "memory");
        }
        __syncthreads();    // per-wave vmcnt(0) drain precedes the barrier
        if (tid == 0) atomicAdd(&zcnt[dirn * 16 + ty], 1u);   // device-scope
        return;
    }

    // ================= LSTM role (R0 verbatim + tile-flag check) =================
    const int bid = blockIdx.x;
    const int d = bid >> 5;          // 0 fwd, 1 bwd
    const int k = bid & 31;
    const float* zin = d ? zin_b : zin_f;
    const float* Whh = d ? Whh_b : Whh_f;
    unsigned int* hw = d ? hw_b : hw_f;

    const int q = tid >> 6;          // wave = column segment (128 cols)
    const int r = tid & 63;          // gate row within wg
    const int gate = r >> 4, jj = r & 15;
    const int grow = gate * HH + k * 16 + jj;      // global gate row [0,2048)

    const f4* wp = (const f4*)(Whh + (size_t)grow * HH + q * 128);
    f4 w[32];
#pragma unroll
    for (int i = 0; i < 32; ++i) w[i] = wp[i];     // plain loads: correct waitcnt
#pragma unroll
    for (int i = 0; i < 32; ++i)
        asm volatile("" : "+a"(w[i]));             // home the values in AGPRs

    float c = 0.f;
    const int l = tid;               // wave0 lane id (used when tid<64)
    const int g = l >> 4, j = l & 15;     // gate / unit for gate phase
    const int n16 = k * 16 + j;           // hidden index for gate phase

    int readyty = -1;                // last verified zin tile (wave0 only)

    for (int it = 0; it < TT; ++it) {
        const int t = d ? (TT - 1 - it) : it;

        // wave0: zin value for (gate g, unit j) — issued before the poll
        float z = 0.f;
        if (tid < 64) {
            const int tyc = t >> 7;
            if (tyc != readyty) {            // once per 128 steps, wave-uniform
                const unsigned int* cp = zcnt + d * 16 + tyc;
                unsigned int cv;
                do {
                    asm volatile("global_load_dword %0, %1, off sc0 sc1\n\t"
                                 "s_waitcnt vmcnt(0)"
                                 : "=v"(cv) : "v"(cp) : "memory");
                } while (cv < 16u);
                readyty = tyc;
            }
            z = zin[(size_t)t * G4 + g * HH + n16];
        }

        if (it > 0 && tid < 64) {
            const int tp = d ? (t + 1) : (t - 1);
            const unsigned int* pa = hw + (size_t)tp * HH + l * 8;
            u4 a0, a1;
            for (;;) {
                asm volatile(
                    "global_load_dwordx4 %0, %2, off sc0 sc1\n\t"
                    "global_load_dwordx4 %1, %2, off offset:16 sc0 sc1\n\t"
                    "s_waitcnt vmcnt(0)"
                    : "=v"(a0), "=v"(a1) : "v"(pa) : "memory");
                if (a0.x != SENT && a0.y != SENT && a0.z != SENT && a0.w != SENT &&
                    a1.x != SENT && a1.y != SENT && a1.z != SENT && a1.w != SENT) break;
            }
            u4* hd = (u4*)(hs + l * 8);
            hd[0] = a0; hd[1] = a1;
        }
        __syncthreads();                                   // B1: hs ready

        // keep weights homed in AGPRs across the loop (re-pin each iter)
#pragma unroll
        for (int i = 0; i < 32; ++i) asm volatile("" : "+a"(w[i]));

        float part = 0.f;
        if (it > 0) {
            const f4* hv = ((const f4*)hs) + (q << 5);     // wave-uniform broadcast
#pragma unroll
            for (int i = 0; i < 32; ++i) {
                f4 h4 = hv[i];
                part += w[i].x * h4.x + w[i].y * h4.y + w[i].z * h4.z + w[i].w * h4.w;
            }
        }
        zb[tid] = part;                                    // zb[q*64 + r]
        __syncthreads();                                   // B2: partials ready

        if (tid < 64) {
            // same summation order as R0 (bit-exact): qq = 0..3
            float s = zb[l] + zb[64 + l] + zb[128 + l] + zb[192 + l];
            const float pre = z + s;
            float act;
            if (g == 2) act = tanhf(pre);                  // g gate
            else        act = 1.f / (1.f + expf(-pre));    // i, f, o gates
            const float gi = __shfl(act, j);
            const float gf = __shfl(act, j + 16);
            const float gg = __shfl(act, j + 32);
            const float go = __shfl(act, j + 48);
            if (l < 16) {
                c = gf * c + gi * gg;
                const float hval = go * tanhf(c);
                __hip_atomic_store(&hw[(size_t)t * HH + k * 16 + l],
                                   __float_as_uint(hval),
                                   __ATOMIC_RELAXED, __HIP_MEMORY_SCOPE_AGENT);
            }
        }
        // 2 barriers suffice: hs(it+1) writes (wave0, after B2(it)) cannot
        // race dot reads of hs(it) (before B2(it)); zb(it+1) writes (after
        // B1(it+1)) cannot race gate-phase zb reads (wave0 reaches B1(it+1)
        // only after finishing them).
    }
}

// ---------------------------------------------------------------------------
// Kernel 3: feats[t] = [h_f[t] | h_b[t]] . fc_w[i] + fc_b[i].  One wave per t.
// ---------------------------------------------------------------------------
__global__ void feats_kernel(const float* __restrict__ h_f, const float* __restrict__ h_b,
                             const float* __restrict__ fc_w, const float* __restrict__ fc_b,
                             float* __restrict__ feats)
{
    const int t = blockIdx.x;
    const int l = threadIdx.x;
    float acc[NC] = {0.f, 0.f, 0.f, 0.f, 0.f};
    for (int m = 0; m < 16; ++m) {
        const int cg = l + m * 64;
        const float hv = (cg < HH) ? h_f[(size_t)t * HH + cg]
                                   : h_b[(size_t)t * HH + cg - HH];
#pragma unroll
        for (int i = 0; i < NC; i++) acc[i] += hv * fc_w[i * (2 * HH) + cg];
    }
#pragma unroll
    for (int i = 0; i < NC; i++) {
#pragma unroll
        for (int off = 32; off; off >>= 1) acc[i] += __shfl_xor(acc[i], off);
    }
    if (l == 0) {
#pragma unroll
        for (int i = 0; i < NC; i++) feats[(size_t)t * NC + i] = acc[i] + fc_b[i];
    }
}

// ---------------------------------------------------------------------------
// Kernel 4: Viterbi forward + backtrack. 1 block, 64 threads.
// ---------------------------------------------------------------------------
__global__ void viterbi_kernel(const float* __restrict__ feats,
                               const float* __restrict__ trans,
                               float* __restrict__ out)
{
    __shared__ float fs[TT * NC];
    __shared__ int par[TT];
    __shared__ float pathv[TT];
    const int tid = threadIdx.x;
    for (int i = tid; i < TT * NC; i += 64) fs[i] = feats[i];
    float tr[25];
#pragma unroll
    for (int i = 0; i < 25; i++) tr[i] = trans[i];
    __syncthreads();

    float layer[NC];
#pragma unroll
    for (int i = 0; i < NC; i++) layer[i] = fs[i] + tr[i * 5 + 3];

    for (int s = 0; s < TT - 1; ++s) {
        const float* ft = &fs[(s + 1) * NC];
        float nl[NC]; int pk = 0;
#pragma unroll
        for (int i = 0; i < NC; i++) {
            float best = tr[i * 5 + 0] + layer[0]; int bj = 0;
#pragma unroll
            for (int jj = 1; jj < NC; jj++) {
                const float v = tr[i * 5 + jj] + layer[jj];
                if (v > best) { best = v; bj = jj; }
            }
            nl[i] = ft[i] + best;
            pk |= bj << (3 * i);
        }
#pragma unroll
        for (int i = 0; i < NC; i++) layer[i] = nl[i];
        if (tid == 0) par[s] = pk;
    }
    float best = layer[0] + tr[20]; int idx0 = 0;
#pragma unroll
    for (int jj = 1; jj < NC; jj++) {
        const float v = layer[jj] + tr[20 + jj];
        if (v > best) { best = v; idx0 = jj; }
    }
    __syncthreads();
    if (tid == 0) {
        pathv[TT - 1] = (float)idx0;
        int idx = idx0;
        for (int s = TT - 2; s >= 0; --s) {
            idx = (par[s] >> (3 * idx)) & 7;
            pathv[s] = (float)idx;
        }
        out[TT] = best;
    }
    __syncthreads();
    for (int i = tid; i < TT; i += 64) out[i] = pathv[i];
}

// ---------------------------------------------------------------------------
extern "C" void kernel_launch(void* const* d_in, const int* in_sizes, int n_in,
                              void* d_out, int out_size, void* d_ws, size_t ws_size,
                              hipStream_t stream) {
    const int*   sent   = (const int*)d_in[0];
    const float* emb    = (const float*)d_in[1];
    const float* Wih_f  = (const float*)d_in[2];
    const float* Whh_f  = (const float*)d_in[3];
    const float* bih_f  = (const float*)d_in[4];
    const float* bhh_f  = (const float*)d_in[5];
    const float* Wih_b  = (const float*)d_in[6];
    const float* Whh_b  = (const float*)d_in[7];
    const float* bih_b  = (const float*)d_in[8];
    const float* bhh_b  = (const float*)d_in[9];
    const float* fc_w   = (const float*)d_in[10];
    const float* fc_b   = (const float*)d_in[11];
    const float* trans  = (const float*)d_in[12];
    float* out = (float*)d_out;

    char* ws = (char*)d_ws;
    float* zin_f = (float*)ws;                                   // 16 MB @ 0
    float* zin_b = (float*)(ws + (size_t)16777216);              // 16 MB @ 16M
    unsigned int* hw_f = (unsigned int*)(ws + (size_t)33554432); //  4 MB @ 32M
    unsigned int* hw_b = (unsigned int*)(ws + (size_t)37748736); //  4 MB @ 36M
    float* feats = (float*)(ws + (size_t)41943040);              // 40 KB @ 40M
    unsigned int* zcnt = (unsigned int*)(ws + (size_t)42008576); // 128 B @ 40M+64K

    // OWN the sentinel: h buffers = 0xFFFFFFFF (-NaN, impossible h)
    hipMemsetAsync(hw_f, 0xFF, (size_t)8388608, stream);         // covers hw_f + hw_b
    hipMemsetAsync(zcnt, 0, (size_t)128, stream);                // zin tile flags

    fused_main<<<576, 256, 0, stream>>>(sent, emb,
                                        Wih_f, bih_f, bhh_f,
                                        Wih_b, bih_b, bhh_b,
                                        Whh_f, Whh_b,
                                        zin_f, zin_b, hw_f, hw_b, zcnt);

    feats_kernel<<<TT, 64, 0, stream>>>((const float*)hw_f, (const float*)hw_b,
                                        fc_w, fc_b, feats);

    viterbi_kernel<<<1, 64, 0, stream>>>(feats, trans, out);
}

// Round 7
// 4729.276 us; speedup vs baseline: 1.1237x; 1.0108x over previous
//
#include <hip/hip_runtime.h>

#define TT 2048
#define WD 768
#define HH 512
#define G4 2048      // 4*H
#define NC 5
#define SENT 0xFFFFFFFFu   // owned sentinel (-NaN); |h|<1 can never produce it.
                           // h buffers memset to 0xFF at every launch.

typedef float f4 __attribute__((ext_vector_type(4)));
typedef unsigned int u4 __attribute__((ext_vector_type(4)));

// ---------------------------------------------------------------------------
// FUSED kernel: 576 wgs.
//   wgs   0..63 : LSTM recurrence — R0 protocol VERBATIM (3869-3875 us proven)
//                 + R6 zin tile-flag check + NEW feats tail (poll h rows with
//                 the SAME proven sentinel probe, compute feats bit-exactly).
//   wgs 64..575 : zin GEMM — R0 arithmetic VERBATIM, t-tiles ordered
//                 fwd-ascending / bwd-descending (R6-proven overlay).
//
// R6 measurement: fused 4043 us, total 4780 -> 737 us tail was feats+viterbi.
// This round folds feats into the fused kernel's tail (each lstm wg handles
// 32 t's after its loop; h rows are write-once and essentially complete by
// then, so the sentinel polls succeed immediately) and leaves the recurrence
// and GEMM roles untouched.
// ---------------------------------------------------------------------------
__global__ __launch_bounds__(256, 1) void fused_main(
    const int* __restrict__ sent, const float* __restrict__ emb,
    const float* __restrict__ Wih_f, const float* __restrict__ bih_f, const float* __restrict__ bhh_f,
    const float* __restrict__ Wih_b, const float* __restrict__ bih_b, const float* __restrict__ bhh_b,
    const float* __restrict__ Whh_f, const float* __restrict__ Whh_b,
    float* __restrict__ zin_f, float* __restrict__ zin_b,
    unsigned int* __restrict__ hw_f, unsigned int* __restrict__ hw_b,
    unsigned int* __restrict__ zcnt,
    const float* __restrict__ fc_w, const float* __restrict__ fc_b,
    float* __restrict__ feats)
{
    __shared__ float As[16][128];
    __shared__ float Bs[16][128];
    __shared__ float hs[HH];
    __shared__ float zb[256];

    const int tid = threadIdx.x;

    if (blockIdx.x >= 64) {
        // ================= GEMM role (R6 verbatim) =================
        const int lin  = blockIdx.x - 64;      // [0,512)
        const int pair = lin >> 5;             // [0,16): production order
        const int sub  = lin & 31;
        const int dirn = sub & 1;
        const int gx   = sub >> 1;             // [0,16)
        const int ty   = dirn ? (15 - pair) : pair;   // bwd consumes high t first

        const float* Wih = dirn ? Wih_b : Wih_f;
        const float* bih = dirn ? bih_b : bih_f;
        const float* bhh = dirn ? bhh_b : bhh_f;
        float* zin = dirn ? zin_b : zin_f;

        const int t0 = ty * 128;
        const int g0 = gx * 128;
        const int tm = tid >> 4, tn = tid & 15;

        float acc[8][8];
#pragma unroll
        for (int a = 0; a < 8; a++)
#pragma unroll
            for (int b = 0; b < 8; b++) acc[a][b] = 0.f;

        for (int kt = 0; kt < 48; ++kt) {
            const int k0 = kt * 16;
#pragma unroll
            for (int u = 0; u < 2; ++u) {
                const int s = tid * 2 + u;
                const int m = s >> 2, kq = s & 3;
                const int rowA = sent[t0 + m];
                float4 av = *(const float4*)(emb + (size_t)rowA * WD + k0 + kq * 4);
                As[kq * 4 + 0][m] = av.x; As[kq * 4 + 1][m] = av.y;
                As[kq * 4 + 2][m] = av.z; As[kq * 4 + 3][m] = av.w;
                float4 bv = *(const float4*)(Wih + (size_t)(g0 + m) * WD + k0 + kq * 4);
                Bs[kq * 4 + 0][m] = bv.x; Bs[kq * 4 + 1][m] = bv.y;
                Bs[kq * 4 + 2][m] = bv.z; Bs[kq * 4 + 3][m] = bv.w;
            }
            __syncthreads();
#pragma unroll
            for (int kk = 0; kk < 16; ++kk) {
                float4 a0 = *(const float4*)&As[kk][tm * 8];
                float4 a1 = *(const float4*)&As[kk][tm * 8 + 4];
                float4 b0 = *(const float4*)&Bs[kk][tn * 8];
                float4 b1 = *(const float4*)&Bs[kk][tn * 8 + 4];
                float av8[8] = {a0.x, a0.y, a0.z, a0.w, a1.x, a1.y, a1.z, a1.w};
                float bv8[8] = {b0.x, b0.y, b0.z, b0.w, b1.x, b1.y, b1.z, b1.w};
#pragma unroll
                for (int a = 0; a < 8; a++)
#pragma unroll
                    for (int b = 0; b < 8; b++) acc[a][b] += av8[a] * bv8[b];
            }
            __syncthreads();
        }
        float bias[8];
#pragma unroll
        for (int b = 0; b < 8; b++) { int g = g0 + tn * 8 + b; bias[b] = bih[g] + bhh[g]; }
#pragma unroll
        for (int a = 0; a < 8; a++) {
            const int t = t0 + tm * 8 + a;
            float* op = zin + (size_t)t * G4 + g0 + tn * 8;
            f4 o0 = {acc[a][0] + bias[0], acc[a][1] + bias[1], acc[a][2] + bias[2], acc[a][3] + bias[3]};
            f4 o1 = {acc[a][4] + bias[4], acc[a][5] + bias[5], acc[a][6] + bias[6], acc[a][7] + bias[7]};
            // sc1: write-through to LLC (within-kernel cross-XCD visibility)
            asm volatile("global_store_dwordx4 %0, %1, off sc1" :: "v"(op), "v"(o0) : "memory");
            asm volatile("global_store_dwordx4 %0, %1, off sc1" :: "v"(op + 4), "v"(o1) : "memory");
        }
        __syncthreads();    // per-wave vmcnt(0) drain precedes the barrier
        if (tid == 0) atomicAdd(&zcnt[dirn * 16 + ty], 1u);   // device-scope
        return;
    }

    // ================= LSTM role (R0 verbatim + tile-flag check) =================
    const int bid = blockIdx.x;
    const int d = bid >> 5;          // 0 fwd, 1 bwd
    const int k = bid & 31;
    const float* zin = d ? zin_b : zin_f;
    const float* Whh = d ? Whh_b : Whh_f;
    unsigned int* hw = d ? hw_b : hw_f;

    const int q = tid >> 6;          // wave = column segment (128 cols)
    const int r = tid & 63;          // gate row within wg
    const int gate = r >> 4, jj = r & 15;
    const int grow = gate * HH + k * 16 + jj;      // global gate row [0,2048)

    const f4* wp = (const f4*)(Whh + (size_t)grow * HH + q * 128);
    f4 w[32];
#pragma unroll
    for (int i = 0; i < 32; ++i) w[i] = wp[i];     // plain loads: correct waitcnt
#pragma unroll
    for (int i = 0; i < 32; ++i)
        asm volatile("" : "+a"(w[i]));             // home the values in AGPRs

    float c = 0.f;
    const int l = tid;               // wave0 lane id (used when tid<64)
    const int g = l >> 4, j = l & 15;     // gate / unit for gate phase
    const int n16 = k * 16 + j;           // hidden index for gate phase

    int readyty = -1;                // last verified zin tile (wave0 only)

    for (int it = 0; it < TT; ++it) {
        const int t = d ? (TT - 1 - it) : it;

        // wave0: zin value for (gate g, unit j) — issued before the poll
        float z = 0.f;
        if (tid < 64) {
            const int tyc = t >> 7;
            if (tyc != readyty) {            // once per 128 steps, wave-uniform
                const unsigned int* cp = zcnt + d * 16 + tyc;
                unsigned int cv;
                do {
                    asm volatile("global_load_dword %0, %1, off sc0 sc1\n\t"
                                 "s_waitcnt vmcnt(0)"
                                 : "=v"(cv) : "v"(cp) : "memory");
                } while (cv < 16u);
                readyty = tyc;
            }
            z = zin[(size_t)t * G4 + g * HH + n16];
        }

        if (it > 0 && tid < 64) {
            const int tp = d ? (t + 1) : (t - 1);
            const unsigned int* pa = hw + (size_t)tp * HH + l * 8;
            u4 a0, a1;
            for (;;) {
                asm volatile(
                    "global_load_dwordx4 %0, %2, off sc0 sc1\n\t"
                    "global_load_dwordx4 %1, %2, off offset:16 sc0 sc1\n\t"
                    "s_waitcnt vmcnt(0)"
                    : "=v"(a0), "=v"(a1) : "v"(pa) : "memory");
                if (a0.x != SENT && a0.y != SENT && a0.z != SENT && a0.w != SENT &&
                    a1.x != SENT && a1.y != SENT && a1.z != SENT && a1.w != SENT) break;
            }
            u4* hd = (u4*)(hs + l * 8);
            hd[0] = a0; hd[1] = a1;
        }
        __syncthreads();                                   // B1: hs ready

        // keep weights homed in AGPRs across the loop (re-pin each iter)
#pragma unroll
        for (int i = 0; i < 32; ++i) asm volatile("" : "+a"(w[i]));

        float part = 0.f;
        if (it > 0) {
            const f4* hv = ((const f4*)hs) + (q << 5);     // wave-uniform broadcast
#pragma unroll
            for (int i = 0; i < 32; ++i) {
                f4 h4 = hv[i];
                part += w[i].x * h4.x + w[i].y * h4.y + w[i].z * h4.z + w[i].w * h4.w;
            }
        }
        zb[tid] = part;                                    // zb[q*64 + r]
        __syncthreads();                                   // B2: partials ready

        if (tid < 64) {
            // same summation order as R0 (bit-exact): qq = 0..3
            float s = zb[l] + zb[64 + l] + zb[128 + l] + zb[192 + l];
            const float pre = z + s;
            float act;
            if (g == 2) act = tanhf(pre);                  // g gate
            else        act = 1.f / (1.f + expf(-pre));    // i, f, o gates
            const float gi = __shfl(act, j);
            const float gf = __shfl(act, j + 16);
            const float gg = __shfl(act, j + 32);
            const float go = __shfl(act, j + 48);
            if (l < 16) {
                c = gf * c + gi * gg;
                const float hval = go * tanhf(c);
                __hip_atomic_store(&hw[(size_t)t * HH + k * 16 + l],
                                   __float_as_uint(hval),
                                   __ATOMIC_RELAXED, __HIP_MEMORY_SCOPE_AGENT);
            }
        }
        // 2 barriers suffice (see R0 comments).
    }

    // ================= feats tail =================
    // Wave (wgid,q) handles t = (wgid*4+q)*8 + n, n=0..7. Rows are write-once;
    // polls use the proven sc0 sc1 sentinel probe. Arithmetic replicates
    // feats_kernel bit-exactly (same lane mapping l=r, same m-order, same
    // xor-butterfly). rowbuf: 1024 floats per wave carved from As/Bs.
    {
        const int wgid = d * 32 + k;
        float* const rowbuf = (q < 2) ? (&As[0][0] + q * 1024)
                                      : (&Bs[0][0] + (q - 2) * 1024);
        for (int n = 0; n < 8; ++n) {
            const int t = (wgid * 4 + q) * 8 + n;
            // poll h_f[t] row: lane r -> floats r*8..r*8+7
            {
                const unsigned int* pa = hw_f + (size_t)t * HH + r * 8;
                u4 a0, a1;
                for (;;) {
                    asm volatile(
                        "global_load_dwordx4 %0, %2, off sc0 sc1\n\t"
                        "global_load_dwordx4 %1, %2, off offset:16 sc0 sc1\n\t"
                        "s_waitcnt vmcnt(0)"
                        : "=v"(a0), "=v"(a1) : "v"(pa) : "memory");
                    if (a0.x != SENT && a0.y != SENT && a0.z != SENT && a0.w != SENT &&
                        a1.x != SENT && a1.y != SENT && a1.z != SENT && a1.w != SENT) break;
                }
                u4* dstp = (u4*)(rowbuf + r * 8);
                dstp[0] = a0; dstp[1] = a1;
            }
            // poll h_b[t] row -> rowbuf[512..1023]
            {
                const unsigned int* pa = hw_b + (size_t)t * HH + r * 8;
                u4 a0, a1;
                for (;;) {
                    asm volatile(
                        "global_load_dwordx4 %0, %2, off sc0 sc1\n\t"
                        "global_load_dwordx4 %1, %2, off offset:16 sc0 sc1\n\t"
                        "s_waitcnt vmcnt(0)"
                        : "=v"(a0), "=v"(a1) : "v"(pa) : "memory");
                    if (a0.x != SENT && a0.y != SENT && a0.z != SENT && a0.w != SENT &&
                        a1.x != SENT && a1.y != SENT && a1.z != SENT && a1.w != SENT) break;
                }
                u4* dstp = (u4*)(rowbuf + HH + r * 8);
                dstp[0] = a0; dstp[1] = a1;
            }
            // feats_kernel arithmetic, bit-exact (l := r); intra-wave LDS
            // write->read without barrier is the R3-proven pattern.
            float facc[NC] = {0.f, 0.f, 0.f, 0.f, 0.f};
            for (int m = 0; m < 16; ++m) {
                const int cg = r + m * 64;
                const float hv = rowbuf[cg];   // [h_f | h_b] layout == feats_kernel's
#pragma unroll
                for (int i = 0; i < NC; i++) facc[i] += hv * fc_w[i * (2 * HH) + cg];
            }
#pragma unroll
            for (int i = 0; i < NC; i++) {
#pragma unroll
                for (int off = 32; off; off >>= 1) facc[i] += __shfl_xor(facc[i], off);
            }
            if (r == 0) {
#pragma unroll
                for (int i = 0; i < NC; i++) feats[(size_t)t * NC + i] = facc[i] + fc_b[i];
            }
        }
    }
}

// ---------------------------------------------------------------------------
// Viterbi: forward scan numerically IDENTICAL (one-step ft prefetch is a
// scheduling-only change); backtrack parallelized EXACTLY via per-chunk
// integer pointer-map composition (64 lanes x 32-step chunks).
// ---------------------------------------------------------------------------
__global__ void viterbi_kernel(const float* __restrict__ feats,
                               const float* __restrict__ trans,
                               float* __restrict__ out)
{
    __shared__ float fs[TT * NC];
    __shared__ int par[TT];
    __shared__ float pathv[TT];
    __shared__ unsigned int maps[64];
    __shared__ int bidx[64];
    const int tid = threadIdx.x;
    for (int i = tid; i < TT * NC; i += 64) fs[i] = feats[i];
    float tr[25];
#pragma unroll
    for (int i = 0; i < 25; i++) tr[i] = trans[i];
    __syncthreads();

    float layer[NC];
#pragma unroll
    for (int i = 0; i < NC; i++) layer[i] = fs[i] + tr[i * 5 + 3];

    float ftc[NC];
#pragma unroll
    for (int i = 0; i < NC; i++) ftc[i] = fs[1 * NC + i];

    for (int s = 0; s < TT - 1; ++s) {
        // prefetch next step's feats (latency hiding; no numeric change)
        const int sp = (s + 2 < TT) ? (s + 2) : (TT - 1);
        float ftn[NC];
#pragma unroll
        for (int i = 0; i < NC; i++) ftn[i] = fs[sp * NC + i];

        float nl[NC]; int pk = 0;
#pragma unroll
        for (int i = 0; i < NC; i++) {
            float best = tr[i * 5 + 0] + layer[0]; int bj = 0;
#pragma unroll
            for (int jj = 1; jj < NC; jj++) {
                const float v = tr[i * 5 + jj] + layer[jj];
                if (v > best) { best = v; bj = jj; }
            }
            nl[i] = ftc[i] + best;
            pk |= bj << (3 * i);
        }
#pragma unroll
        for (int i = 0; i < NC; i++) { layer[i] = nl[i]; ftc[i] = ftn[i]; }
        if (tid == 0) par[s] = pk;
    }
    float best = layer[0] + tr[20]; int idx0 = 0;
#pragma unroll
    for (int jj = 1; jj < NC; jj++) {
        const float v = layer[jj] + tr[20 + jj];
        if (v > best) { best = v; idx0 = jj; }
    }
    __syncthreads();

    // ---- parallel backtrack (integer-exact) ----
    // chunk c = tid: s in [32c, min(32c+31, TT-2)]
    const int slo = tid * 32;
    const int shi0 = slo + 31;
    const int shi = (shi0 < TT - 1) ? shi0 : (TT - 2);
    int preg[32];
#pragma unroll
    for (int u = 0; u < 32; ++u) {
        int su = slo + u; if (su > TT - 2) su = TT - 2;   // clamp (unused dups)
        preg[u] = par[su];
    }
    // build map: entering idx e (at s=shi+1) -> idx at s=slo
    int m0 = 0, m1 = 1, m2 = 2, m3 = 3, m4 = 4;
    for (int s = shi; s >= slo; --s) {
        const int pv = preg[s - slo];
        m0 = (pv >> (3 * m0)) & 7;
        m1 = (pv >> (3 * m1)) & 7;
        m2 = (pv >> (3 * m2)) & 7;
        m3 = (pv >> (3 * m3)) & 7;
        m4 = (pv >> (3 * m4)) & 7;
    }
    maps[tid] = (unsigned)(m0 | (m1 << 3) | (m2 << 6) | (m3 << 9) | (m4 << 12));
    __syncthreads();
    if (tid == 0) {
        int e = idx0;                     // idx entering chunk 63 (= idx_{TT-1})
        for (int cc = 63; cc >= 0; --cc) {
            bidx[cc] = e;
            e = (int)((maps[cc] >> (3 * e)) & 7u);
        }
    }
    __syncthreads();
    {
        int e = bidx[tid];
        for (int s = shi; s >= slo; --s) {
            e = (preg[s - slo] >> (3 * e)) & 7;
            pathv[s] = (float)e;
        }
    }
    if (tid == 0) { pathv[TT - 1] = (float)idx0; out[TT] = best; }
    __syncthreads();
    for (int i = tid; i < TT; i += 64) out[i] = pathv[i];
}

// ---------------------------------------------------------------------------
extern "C" void kernel_launch(void* const* d_in, const int* in_sizes, int n_in,
                              void* d_out, int out_size, void* d_ws, size_t ws_size,
                              hipStream_t stream) {
    const int*   sent   = (const int*)d_in[0];
    const float* emb    = (const float*)d_in[1];
    const float* Wih_f  = (const float*)d_in[2];
    const float* Whh_f  = (const float*)d_in[3];
    const float* bih_f  = (const float*)d_in[4];
    const float* bhh_f  = (const float*)d_in[5];
    const float* Wih_b  = (const float*)d_in[6];
    const float* Whh_b  = (const float*)d_in[7];
    const float* bih_b  = (const float*)d_in[8];
    const float* bhh_b  = (const float*)d_in[9];
    const float* fc_w   = (const float*)d_in[10];
    const float* fc_b   = (const float*)d_in[11];
    const float* trans  = (const float*)d_in[12];
    float* out = (float*)d_out;

    char* ws = (char*)d_ws;
    float* zin_f = (float*)ws;                                   // 16 MB @ 0
    float* zin_b = (float*)(ws + (size_t)16777216);              // 16 MB @ 16M
    unsigned int* hw_f = (unsigned int*)(ws + (size_t)33554432); //  4 MB @ 32M
    unsigned int* hw_b = (unsigned int*)(ws + (size_t)37748736); //  4 MB @ 36M
    float* feats = (float*)(ws + (size_t)41943040);              // 40 KB @ 40M
    unsigned int* zcnt = (unsigned int*)(ws + (size_t)42008576); // 128 B @ 40M+64K

    // OWN the sentinel: h buffers = 0xFFFFFFFF (-NaN, impossible h)
    hipMemsetAsync(hw_f, 0xFF, (size_t)8388608, stream);         // covers hw_f + hw_b
    hipMemsetAsync(zcnt, 0, (size_t)128, stream);                // zin tile flags

    fused_main<<<576, 256, 0, stream>>>(sent, emb,
                                        Wih_f, bih_f, bhh_f,
                                        Wih_b, bih_b, bhh_b,
                                        Whh_f, Whh_b,
                                        zin_f, zin_b, hw_f, hw_b, zcnt,
                                        fc_w, fc_b, feats);

    viterbi_kernel<<<1, 64, 0, stream>>>(feats, trans, out);
}